// Round 2
// baseline (61.066 us; speedup 1.0000x reference)
//
#include <hip/hip_runtime.h>

// arDCA: out[n,q] = softmax_q( h[400,q] + sum_{j<400} J[400,q,j,tok(n,j)] )
// X one-hot [4096,400,21] f32. Pipeline:
//   K0: Jq2[j][t][q]  <- J[400,q,j,t]        (705 KB, L2-resident)
//   K1: tok[n*400+j]  <- argmax_a X[n,j,a]   (pure-linear X stream, 137.6 MB)
//   K2: gather-accumulate + softmax, coalesced [n][q] output
// N=4096, RES=400, Q=21, L=512.

#define QA    21
#define RESI  400
#define NSEQ  4096
#define JQ2_ELEMS (RESI*QA*QA)    // 176400 floats (705.6 KB)
#define TOK_BYTES (NSEQ*RESI)     // 1638400 bytes

// K0: Jq2[(j*21+a)*21 + q] = J[((8400+q)*512 + j)*21 + a]
// Input-coalesced: for fixed q, (j*21+a) is a contiguous 8400-float run.
__global__ __launch_bounds__(256) void k0_jq2(const float* __restrict__ J,
                                              float* __restrict__ Jq2) {
    int s = blockIdx.x * 256 + threadIdx.x;
    if (s >= JQ2_ELEMS) return;
    int q  = s / 8400;            // 0..20
    int ja = s - q * 8400;        // j*21 + a, contiguous
    float v = J[(8400 + q) * 10752 + ja];
    Jq2[ja * 21 + q] = v;         // scattered store, write-combined in L2
}

// K1: tokenize. Block = 1024 contiguous cells (cell = n*400+j), 4 substages
// of 256 cells. X reads are perfectly linear float4; LDS read stride 21
// floats -> 2-way bank alias (free). tok write = 64B/wave contiguous.
__global__ __launch_bounds__(256) void k1_tok(const float4* __restrict__ Xf4,
                                              unsigned char* __restrict__ tok) {
    __shared__ float4 xs4[1344];            // 256 cells x 21 floats = 21504 B
    const float* xs = (const float*)xs4;
    const int tid = threadIdx.x;
    const int b   = blockIdx.x;
    for (int s = 0; s < 4; ++s) {
        const int base4 = b * 5376 + s * 1344;
        #pragma unroll
        for (int k = 0; k < 6; ++k) {
            int i = tid + (k << 8);
            if (i < 1344) xs4[i] = Xf4[base4 + i];
        }
        __syncthreads();
        float acc = 0.f;
        const float* row = xs + tid * 21;
        #pragma unroll
        for (int a = 0; a < 21; ++a)
            acc = fmaf(row[a], (float)a, acc);   // one-hot dot-iota, exact
        tok[b * 1024 + s * 256 + tid] = (unsigned char)(int)(acc + 0.5f);
        __syncthreads();
    }
}

// K2: per wave: lanes = (q = l%21, nsub = l/21) -> 3 n x 21 q (lane 63 idle).
// Per j: 1 broadcast tok byte (3 distinct addrs) + 1 gather spanning 3 runs
// of 84 contiguous bytes in L2-hot Jq2. Softmax + coalesced out fused.
__global__ __launch_bounds__(256) void k2_accsm(const unsigned char* __restrict__ tok,
                                               const float* __restrict__ Jq2,
                                               const float* __restrict__ h,
                                               float* __restrict__ out) {
    __shared__ float lg[252];               // [12 n][21 q]
    const int tid  = threadIdx.x;
    const int w    = tid >> 6, l = tid & 63;
    const int q    = l % 21;
    const int nsub = l / 21;                // 0..2 (3 for l==63)
    const int n    = blockIdx.x * 12 + w * 3 + nsub;
    const bool act = (l < 63) && (n < NSEQ);
    if (act) {
        float acc = 0.f;
        const unsigned char* tr = tok + n * 400;
        #pragma unroll 8
        for (int j = 0; j < 400; ++j) {
            int t = tr[j];
            acc += Jq2[j * 441 + t * 21 + q];
        }
        lg[w * 63 + l] = acc + h[8400 + q];
    }
    __syncthreads();
    if (tid < 252) {
        int nl = tid / 21, qq = tid - nl * 21;
        int gn = blockIdx.x * 12 + nl;
        if (gn < NSEQ) {
            const float* rowp = lg + nl * 21;
            float m = -1e30f;
            #pragma unroll
            for (int a = 0; a < 21; ++a) m = fmaxf(m, rowp[a]);
            float ssum = 0.f;
            #pragma unroll
            for (int a = 0; a < 21; ++a) ssum += __expf(rowp[a] - m);
            out[gn * 21 + qq] = __expf(rowp[qq] - m) / ssum;  // coalesced
        }
    }
}

extern "C" void kernel_launch(void* const* d_in, const int* in_sizes, int n_in,
                              void* d_out, int out_size, void* d_ws, size_t ws_size,
                              hipStream_t stream) {
    const float* X = (const float*)d_in[0];   // [4096,400,21]
    const float* h = (const float*)d_in[1];   // [512,21]
    const float* J = (const float*)d_in[2];   // [512,21,512,21]
    float* out = (float*)d_out;               // [4096,21]

    float* Jq2 = (float*)d_ws;                          // 176400 floats
    unsigned char* tok = (unsigned char*)(Jq2 + JQ2_ELEMS);  // 1638400 bytes
    // total ws use: ~2.3 MB

    k0_jq2<<<(JQ2_ELEMS + 255) / 256, 256, 0, stream>>>(J, Jq2);
    k1_tok<<<1600, 256, 0, stream>>>((const float4*)X, tok);
    k2_accsm<<<342, 256, 0, stream>>>(tok, Jq2, h, out);
}

// Round 3
// 40.023 us; speedup vs baseline: 1.5258x; 1.5258x over previous
//
#include <hip/hip_runtime.h>

// arDCA: out[n,q] = softmax_q( h[400,q] + sum_{j<400} J[400,q,j,tok(n,j)] )
// K0: Jq2[j][t][q] <- J[400,q,j,t]   (705 KB, L2-resident)
// K1: fused tokenize+gather-accumulate, async double-buffered X staging,
//     counted vmcnt (no barrier drain), partials P[c][tile][252]
// K2: reduce partials + h + softmax, coalesced
// N=4096, RES=400, Q=21, L=512.

#define QA    21
#define RESI  400
#define NSEQ  4096
#define NT    12                 // n per block (K1/K2)
#define NBX   342                // ceil(4096/12)
#define NCH   5                  // j-chunks
#define CHJ   80                 // j per chunk
#define SJ    16                 // j per stage
#define NST   5                  // stages per chunk
#define STAGE_F  (NT*SJ*QA)      // 4032 floats per stage
#define STAGE_V4 (STAGE_F/4)     // 1008 dwordx4 loads per stage
#define JQ2_ELEMS (RESI*QA*QA)   // 176400
#define P_PER (NT*QA)            // 252
#define P_ELEMS (NCH*NBX*P_PER)  // 430920

#define GLOAD_LDS16(g, l)                                                     \
    __builtin_amdgcn_global_load_lds(                                         \
        (const __attribute__((address_space(1))) void*)(g),                   \
        (__attribute__((address_space(3))) void*)(l), 16, 0, 0)

// ---------------- K0: Jq2[(j*21+a)*21+q] = J[((8400+q)*512+j)*21+a] --------
__global__ __launch_bounds__(256) void k0_jq2(const float* __restrict__ J,
                                              float* __restrict__ Jq2) {
    int s = blockIdx.x * 256 + threadIdx.x;
    if (s >= JQ2_ELEMS) return;
    int q  = s / 8400;            // 0..20
    int ja = s - q * 8400;        // j*21+a, contiguous -> coalesced read
    Jq2[ja * 21 + q] = J[(8400 + q) * 10752 + ja];
}

// ---------------- K1: fused tokenize + accumulate --------------------------
// block: 256 thr; tile = 12 n x 80 j, 5 stages of 16 j.
// stage buf: [12 rows][16j*21a floats], rows 16B-aligned (j0 multiple of 4).
__global__ __launch_bounds__(256) void k1_main(const float* __restrict__ X,
                                               const float* __restrict__ Jq2,
                                               float* __restrict__ P) {
    __shared__ float buf[2][STAGE_F];     // 32256 B
    __shared__ int   tokb[2][NT * SJ];    // 1536 B

    const int tid = threadIdx.x;
    const int bx  = blockIdx.x;
    const int c   = blockIdx.y;
    const int n0  = bx * NT;
    const int j0  = c * CHJ;

    const int w    = tid >> 6, l = tid & 63;
    const int q    = l % 21;
    const int ns   = l / 21;              // 0..2 valid
    const int nloc = w * 3 + ns;          // 0..11
    const bool act = (l < 63);

    // issue one stage's 1008 dwordx4 as global_load_lds (4 instr/wave, uniform)
    auto issue = [&](int s) {
        const int jb = j0 + s * SJ;
        float* dst = &buf[s & 1][0];
        #pragma unroll
        for (int k = 0; k < 4; ++k) {
            int e = tid + (k << 8);
            if (e < STAGE_V4) {           // k<3 always true; k==3: lanes e<1008
                int row = e / 84;         // 84 dwordx4 per n-row
                int col = e - row * 84;
                int nr  = n0 + row;
                if (nr >= NSEQ) nr = n0;  // tail-block clamp (data unused)
                const float* gp = X + (nr * RESI + jb) * QA + (col << 2);
                GLOAD_LDS16(gp, dst + (e << 2));
            }
        }
    };

    float acc = 0.f;
    issue(0);

    #pragma unroll
    for (int s = 0; s < NST; ++s) {
        const int p = s & 1;
        if (s + 1 < NST) {
            issue(s + 1);
            asm volatile("s_waitcnt vmcnt(4)" ::: "memory");  // stage s landed
        } else {
            asm volatile("s_waitcnt vmcnt(0)" ::: "memory");
        }
        __builtin_amdgcn_s_barrier();
        __builtin_amdgcn_sched_barrier(0);

        // tokenize: 192 cells, one per thread; iota-dot is exact for one-hot
        if (tid < NT * SJ) {
            const int r = tid >> 4, jj = tid & 15;
            const float* cell = &buf[p][r * (SJ * QA) + jj * QA];
            float fa = 0.f;
            #pragma unroll
            for (int a = 0; a < QA; ++a) fa = fmaf(cell[a], (float)a, fa);
            tokb[p][tid] = (int)(fa + 0.5f);
        }
        asm volatile("s_waitcnt lgkmcnt(0)" ::: "memory");
        __builtin_amdgcn_s_barrier();
        __builtin_amdgcn_sched_barrier(0);

        // accumulate: per wave 21q x 3n; gathers = 3 runs of 84B in L2-hot Jq2
        if (act) {
            const int jb441 = (j0 + s * SJ) * 441;
            const int4* tp = (const int4*)&tokb[p][nloc * SJ];
            #pragma unroll
            for (int g = 0; g < 4; ++g) {
                int4 t4 = tp[g];
                acc += Jq2[jb441 + (4 * g + 0) * 441 + t4.x * 21 + q];
                acc += Jq2[jb441 + (4 * g + 1) * 441 + t4.y * 21 + q];
                acc += Jq2[jb441 + (4 * g + 2) * 441 + t4.z * 21 + q];
                acc += Jq2[jb441 + (4 * g + 3) * 441 + t4.w * 21 + q];
            }
        }
    }

    // partial write via LDS bounce (buf free after last tokenize barrier)
    float* pb = &buf[0][0];
    if (act) pb[q * NT + nloc] = acc;
    __syncthreads();
    if (tid < P_PER)
        P[(c * NBX + bx) * P_PER + tid] = pb[tid];   // coalesced
}

// ---------------- K2: reduce partials + h + softmax ------------------------
__global__ __launch_bounds__(256) void k2_finish(const float* __restrict__ P,
                                                 const float* __restrict__ h,
                                                 float* __restrict__ out) {
    __shared__ float sm[P_PER];          // [q][nl] layout, q*12+nl
    const int bx = blockIdx.x, tid = threadIdx.x;
    if (tid < P_PER) {
        float v = 0.f;
        #pragma unroll
        for (int cc = 0; cc < NCH; ++cc)
            v += P[(cc * NBX + bx) * P_PER + tid];   // coalesced
        sm[tid] = v + h[8400 + tid / NT];
    }
    __syncthreads();
    if (tid < P_PER) {
        const int nl = tid / QA, q2 = tid - nl * QA;
        const int n  = bx * NT + nl;
        if (n < NSEQ) {
            float m = -1e30f;
            #pragma unroll
            for (int a = 0; a < QA; ++a) m = fmaxf(m, sm[a * NT + nl]);
            float den = 0.f;
            #pragma unroll
            for (int a = 0; a < QA; ++a) den += __expf(sm[a * NT + nl] - m);
            out[n * QA + q2] = __expf(sm[q2 * NT + nl] - m) / den;  // coalesced
        }
    }
}

extern "C" void kernel_launch(void* const* d_in, const int* in_sizes, int n_in,
                              void* d_out, int out_size, void* d_ws, size_t ws_size,
                              hipStream_t stream) {
    const float* X = (const float*)d_in[0];   // [4096,400,21] one-hot
    const float* h = (const float*)d_in[1];   // [512,21]
    const float* J = (const float*)d_in[2];   // [512,21,512,21]
    float* out = (float*)d_out;               // [4096,21]

    float* Jq2 = (float*)d_ws;                // 176400 floats
    float* P   = Jq2 + JQ2_ELEMS;             // 430920 floats (~2.43 MB total)

    k0_jq2<<<(JQ2_ELEMS + 255) / 256, 256, 0, stream>>>(J, Jq2);
    k1_main<<<dim3(NBX, NCH), 256, 0, stream>>>(X, Jq2, P);
    k2_finish<<<NBX, 256, 0, stream>>>(P, h, out);
}